// Round 2
// baseline (252.016 us; speedup 1.0000x reference)
//
#include <hip/hip_runtime.h>

#define N_ 4
#define L_ 1024
#define H_ 8
#define D_ 64

typedef _Float16 f16x8 __attribute__((ext_vector_type(8)));
typedef float f32x4 __attribute__((ext_vector_type(4)));
typedef float f32x2 __attribute__((ext_vector_type(2)));

#define MFMA(A, B, C) __builtin_amdgcn_mfma_f32_16x16x32_f16(A, B, C, 0, 0, 0)

__device__ __forceinline__ ushort f2h(float x) {
    union { _Float16 h; ushort u; } c;
    c.h = (_Float16)x;
    return c.u;
}
__device__ __forceinline__ float h2f(ushort u) {
    union { ushort u; _Float16 h; } c;
    c.u = u;
    return (float)c.h;
}
__device__ __forceinline__ f16x8 ld8(const ushort* p) {
    return *(const f16x8*)p;
}
__device__ __forceinline__ f16x8 negf(f16x8 a) {
    uint4 u = __builtin_bit_cast(uint4, a);
    u.x ^= 0x80008000u; u.y ^= 0x80008000u; u.z ^= 0x80008000u; u.w ^= 0x80008000u;
    return __builtin_bit_cast(f16x8, u);
}

// ---- convert Q,K: fp32 [n][l][h][d] -> f16 [aid][n][h][l][d], aid in {qr,qi,kr,ki}
__global__ void cvt_qk(const float* __restrict__ q_r, const float* __restrict__ q_i,
                       const float* __restrict__ k_r, const float* __restrict__ k_i,
                       ushort* __restrict__ dst) {
    int gid = blockIdx.x * 256 + threadIdx.x;   // 0..2097151 (x4 elems each)
    int aid = gid >> 19;
    int idx = (gid & 0x7FFFF) << 2;             // flat [n][h][l][d]
    int d  = idx & 63;
    int l  = (idx >> 6) & 1023;
    int hh = (idx >> 16) & 7;
    int n  = idx >> 19;
    const float* src = aid == 0 ? q_r : aid == 1 ? q_i : aid == 2 ? k_r : k_i;
    const float4 v = *(const float4*)(src + (((long)n * 1024 + l) * 8 + hh) * 64 + d);
    ushort4 o = make_ushort4(f2h(v.x), f2h(v.y), f2h(v.z), f2h(v.w));
    *(ushort4*)(dst + ((long)aid << 21) + idx) = o;
}

// ---- convert V: fp32 [n][s][h][d] -> f16 transposed [aid][n][h][d][s]
__global__ void cvt_v(const float* __restrict__ vr, const float* __restrict__ vi,
                      ushort* __restrict__ dst) {
    __shared__ ushort t[64][72];
    int bid = blockIdx.x;
    int aid = bid >> 9;
    int b   = bid & 511;
    int s0  = (b & 15) << 6;
    int hh  = (b >> 4) & 7;
    int n   = b >> 7;
    const float* src = aid ? vi : vr;
    int tid = threadIdx.x;            // 256
    int r  = tid >> 4;                // 0..15
    int cq = (tid & 15) << 2;         // 0,4,..,60
#pragma unroll
    for (int it = 0; it < 4; ++it) {
        int s = s0 + it * 16 + r;
        const float4 v = *(const float4*)(src + (((long)n * 1024 + s) * 8 + hh) * 64 + cq);
        t[it * 16 + r][cq + 0] = f2h(v.x);
        t[it * 16 + r][cq + 1] = f2h(v.y);
        t[it * 16 + r][cq + 2] = f2h(v.z);
        t[it * 16 + r][cq + 3] = f2h(v.w);
    }
    __syncthreads();
#pragma unroll
    for (int it = 0; it < 4; ++it) {
        int dd = it * 16 + r;
        ushort4 o;
        o.x = t[cq + 0][dd]; o.y = t[cq + 1][dd]; o.z = t[cq + 2][dd]; o.w = t[cq + 3][dd];
        *(ushort4*)(dst + ((long)aid << 21) + (((long)n * 8 + hh) * 64 + dd) * 1024 + s0 + cq) = o;
    }
}

// ---- fused complex attention ----
// grid 256 (XCD-swizzled -> (n, l-tile)), block 1024 = 16 waves.
// wave = (h, sh): head h, s-half sh. Each wave owns 8 of 16 s-chunks.
// pass1: per-wave online stats over own chunks, then LDS combine across sh.
// pass2: recompute scores, w -> swizzled LDS, u-MFMA (own head/half),
//        a = mean_h w from all 8 heads' buffers of own sh. u combined via LDS.
__launch_bounds__(1024, 4)
__global__ void attn(const ushort* __restrict__ ws, float* __restrict__ out) {
    extern __shared__ ushort dynlds[];              // 64KB: [sh][h][part][16][64] swizzled
    __shared__ float sst[2][8][2][16][2];           // [sh][h][part][row][m,d]

    const int tid  = threadIdx.x;
    const int lane = tid & 63;
    const int wv   = tid >> 6;
    const int h    = wv & 7;
    const int sh   = wv >> 3;
    const int col  = lane & 15;     // C-frag col; also A-frag row
    const int g    = lane >> 4;

    // XCD swizzle: blocks with same bid%8 (same XCD) get contiguous nid range
    const int bid = blockIdx.x;
    const int nid = (bid & 7) * 32 + (bid >> 3);
    const int n   = nid >> 6;
    const int l0  = (nid & 63) << 4;

    const ushort* wsQr = ws;
    const ushort* wsQi = ws + (1l << 21);
    const ushort* wsKr = ws + (2l << 21);
    const ushort* wsKi = ws + (3l << 21);
    const ushort* wsVr = ws + (4l << 21);   // [n][h][d][s]
    const ushort* wsVi = ws + (5l << 21);

    const int nh = n * H_ + h;
    const ushort* Kr = wsKr + ((long)nh << 16);   // [1024][64]
    const ushort* Ki = wsKi + ((long)nh << 16);
    const ushort* Vr = wsVr + ((long)nh << 16);   // [64][1024]
    const ushort* Vi = wsVi + ((long)nh << 16);

    const long qoff = ((long)nh * 1024 + l0 + col) * 64 + g * 8;
    f16x8 qr0 = ld8(wsQr + qoff), qr1 = ld8(wsQr + qoff + 32);
    f16x8 qi0 = ld8(wsQi + qoff), qi1 = ld8(wsQi + qoff + 32);
    f16x8 qn0 = negf(qi0), qn1 = negf(qi1);

    const float SC = 0.125f * 1.44269504088896f;  // scale * log2(e)

    float mR[4], dR[4], mI[4], dI[4];
#pragma unroll
    for (int r = 0; r < 4; ++r) { mR[r] = mI[r] = -1e30f; dR[r] = dI[r] = 0.f; }

    auto compute_scores = [&](int c, f32x4* srT, f32x4* siT) {
#pragma unroll
        for (int sb = 0; sb < 4; ++sb) {
            const int s = c * 64 + sb * 16 + col;
            const ushort* kb = Kr + (long)s * 64 + g * 8;
            f16x8 kr0v = ld8(kb), kr1v = ld8(kb + 32);
            const ushort* kib = Ki + (long)s * 64 + g * 8;
            f16x8 ki0v = ld8(kib), ki1v = ld8(kib + 32);
            f32x4 a0 = {0.f, 0.f, 0.f, 0.f};
            a0 = MFMA(qr0, kr0v, a0); a0 = MFMA(qr1, kr1v, a0);
            a0 = MFMA(qn0, ki0v, a0); a0 = MFMA(qn1, ki1v, a0);
            srT[sb] = a0;
            f32x4 a1 = {0.f, 0.f, 0.f, 0.f};
            a1 = MFMA(qr0, ki0v, a1); a1 = MFMA(qr1, ki1v, a1);
            a1 = MFMA(qi0, kr0v, a1); a1 = MFMA(qi1, kr1v, a1);
            siT[sb] = a1;
        }
    };

    // ---------------- pass 1: softmax stats over own 8 chunks ----------------
    for (int cc = 0; cc < 8; ++cc) {
        const int c = sh * 8 + cc;
        f32x4 srT[4], siT[4];
        compute_scores(c, srT, siT);
#pragma unroll
        for (int r = 0; r < 4; ++r) {
            {
                float v0 = srT[0][r] * SC, v1 = srT[1][r] * SC;
                float v2 = srT[2][r] * SC, v3 = srT[3][r] * SC;
                float mx = fmaxf(fmaxf(v0, v1), fmaxf(v2, v3));
                mx = fmaxf(mx, __shfl_xor(mx, 1));
                mx = fmaxf(mx, __shfl_xor(mx, 2));
                mx = fmaxf(mx, __shfl_xor(mx, 4));
                mx = fmaxf(mx, __shfl_xor(mx, 8));
                float mn = fmaxf(mR[r], mx);
                float ss = exp2f(v0 - mn) + exp2f(v1 - mn) + exp2f(v2 - mn) + exp2f(v3 - mn);
                ss += __shfl_xor(ss, 1); ss += __shfl_xor(ss, 2);
                ss += __shfl_xor(ss, 4); ss += __shfl_xor(ss, 8);
                dR[r] = dR[r] * exp2f(mR[r] - mn) + ss;
                mR[r] = mn;
            }
            {
                float v0 = siT[0][r] * SC, v1 = siT[1][r] * SC;
                float v2 = siT[2][r] * SC, v3 = siT[3][r] * SC;
                float mx = fmaxf(fmaxf(v0, v1), fmaxf(v2, v3));
                mx = fmaxf(mx, __shfl_xor(mx, 1));
                mx = fmaxf(mx, __shfl_xor(mx, 2));
                mx = fmaxf(mx, __shfl_xor(mx, 4));
                mx = fmaxf(mx, __shfl_xor(mx, 8));
                float mn = fmaxf(mI[r], mx);
                float ss = exp2f(v0 - mn) + exp2f(v1 - mn) + exp2f(v2 - mn) + exp2f(v3 - mn);
                ss += __shfl_xor(ss, 1); ss += __shfl_xor(ss, 2);
                ss += __shfl_xor(ss, 4); ss += __shfl_xor(ss, 8);
                dI[r] = dI[r] * exp2f(mI[r] - mn) + ss;
                mI[r] = mn;
            }
        }
    }

    // ---------------- combine stats across s-halves ----------------
    if (col == 0) {
#pragma unroll
        for (int r = 0; r < 4; ++r) {
            *(f32x2*)&sst[sh][h][0][4 * g + r][0] = (f32x2){mR[r], dR[r]};
            *(f32x2*)&sst[sh][h][1][4 * g + r][0] = (f32x2){mI[r], dI[r]};
        }
    }
    __syncthreads();

    float rdR[4], rdI[4];
#pragma unroll
    for (int r = 0; r < 4; ++r) {
        const int row = 4 * g + r;
        {
            f32x2 s0 = *(f32x2*)&sst[0][h][0][row][0];
            f32x2 s1 = *(f32x2*)&sst[1][h][0][row][0];
            float m = fmaxf(s0.x, s1.x);
            float d = s0.y * exp2f(s0.x - m) + s1.y * exp2f(s1.x - m);
            mR[r] = m; rdR[r] = 1.f / d;
        }
        {
            f32x2 s0 = *(f32x2*)&sst[0][h][1][row][0];
            f32x2 s1 = *(f32x2*)&sst[1][h][1][row][0];
            float m = fmaxf(s0.x, s1.x);
            float d = s0.y * exp2f(s0.x - m) + s1.y * exp2f(s1.x - m);
            mI[r] = m; rdI[r] = 1.f / d;
        }
    }

    // ---------------- pass 2: apply over own 8 chunks ----------------
    f32x4 uRe[4], uIm[4];
#pragma unroll
    for (int db = 0; db < 4; ++db) {
        uRe[db] = (f32x4){0.f, 0.f, 0.f, 0.f};
        uIm[db] = (f32x4){0.f, 0.f, 0.f, 0.f};
    }

    const long OFF_UI = 2097152;
    const long OFF_AR = 4194304;
    const long OFF_AI = 8388608;

    ushort* wbr = dynlds + (((sh * 8 + h) * 2 + 0) << 10);
    ushort* wbi = dynlds + (((sh * 8 + h) * 2 + 1) << 10);

    for (int cc = 0; cc < 8; ++cc) {
        const int c = sh * 8 + cc;
        f32x4 srT[4], siT[4];
        compute_scores(c, srT, siT);
#pragma unroll
        for (int sb = 0; sb < 4; ++sb) {
#pragma unroll
            for (int r = 0; r < 4; ++r) {
                const int row = 4 * g + r;
                const int us = (sb * 16 + col) ^ ((row & 7) << 3);
                wbr[row * 64 + us] = f2h(exp2f(srT[sb][r] * SC - mR[r]) * rdR[r]);
                wbi[row * 64 + us] = f2h(exp2f(siT[sb][r] * SC - mI[r]) * rdI[r]);
            }
        }
        __syncthreads();
        // u MFMA: A = w (own head/half), B = V^T slices. swizzled b128 reads.
        const int xr  = ((g ^ (col & 7)) << 3);
        const int xr2 = (((g + 4) ^ (col & 7)) << 3);
        f16x8 wr0 = ld8(&wbr[col * 64 + xr]);
        f16x8 wr1 = ld8(&wbr[col * 64 + xr2]);
        f16x8 wi0 = ld8(&wbi[col * 64 + xr]);
        f16x8 wi1 = ld8(&wbi[col * 64 + xr2]);
        f16x8 wn0 = negf(wi0), wn1 = negf(wi1);
#pragma unroll
        for (int db = 0; db < 4; ++db) {
            const ushort* vrb = Vr + (long)(db * 16 + col) * 1024 + c * 64 + g * 8;
            f16x8 vr0 = ld8(vrb), vr1 = ld8(vrb + 32);
            const ushort* vib = Vi + (long)(db * 16 + col) * 1024 + c * 64 + g * 8;
            f16x8 vi0 = ld8(vib), vi1 = ld8(vib + 32);
            uRe[db] = MFMA(wr0, vr0, uRe[db]); uRe[db] = MFMA(wr1, vr1, uRe[db]);
            uRe[db] = MFMA(wn0, vi0, uRe[db]); uRe[db] = MFMA(wn1, vi1, uRe[db]);
            uIm[db] = MFMA(wr0, vi0, uIm[db]); uIm[db] = MFMA(wr1, vi1, uIm[db]);
            uIm[db] = MFMA(wi0, vr0, uIm[db]); uIm[db] = MFMA(wi1, vr1, uIm[db]);
        }
        // a slice: rows 2h, 2h+1 of own sh's current chunk, summed over heads
#pragma unroll
        for (int rr = 0; rr < 2; ++rr) {
            const int l = 2 * h + rr;
            const int us = lane ^ ((l & 7) << 3);
            float s_r = 0.f, s_i = 0.f;
#pragma unroll
            for (int hh = 0; hh < 8; ++hh) {
                s_r += h2f(dynlds[(((sh * 8 + hh) * 2 + 0) << 10) + l * 64 + us]);
                s_i += h2f(dynlds[(((sh * 8 + hh) * 2 + 1) << 10) + l * 64 + us]);
            }
            const long ai = ((long)n * L_ + l0 + l) * 1024 + c * 64 + lane;
            out[OFF_AR + ai] = s_r * 0.125f;
            out[OFF_AI + ai] = s_i * 0.125f;
        }
        __syncthreads();
    }

    // ---------------- combine u across s-halves, write ----------------
    float* uc = (float*)dynlds;   // 64KB alias, safe after trailing barrier
    if (sh == 1) {
#pragma unroll
        for (int db = 0; db < 4; ++db) {
            *(f32x4*)&uc[(((h * 2 + 0) * 4 + db) * 64 + lane) * 4] = uRe[db];
            *(f32x4*)&uc[(((h * 2 + 1) * 4 + db) * 64 + lane) * 4] = uIm[db];
        }
    }
    __syncthreads();
    if (sh == 0) {
#pragma unroll
        for (int db = 0; db < 4; ++db) {
            f32x4 o0 = *(f32x4*)&uc[(((h * 2 + 0) * 4 + db) * 64 + lane) * 4];
            f32x4 o1 = *(f32x4*)&uc[(((h * 2 + 1) * 4 + db) * 64 + lane) * 4];
            uRe[db] += o0;
            uIm[db] += o1;
#pragma unroll
            for (int r = 0; r < 4; ++r) {
                const int l = l0 + 4 * g + r;
                const int d = db * 16 + col;
                const long base = (((long)n * L_ + l) * H_ + h) * D_ + d;
                out[base] = uRe[db][r];
                out[OFF_UI + base] = uIm[db][r];
            }
        }
    }
}

extern "C" void kernel_launch(void* const* d_in, const int* in_sizes, int n_in,
                              void* d_out, int out_size, void* d_ws, size_t ws_size,
                              hipStream_t stream) {
    const float* qr = (const float*)d_in[0];
    const float* qi = (const float*)d_in[1];
    const float* kr = (const float*)d_in[2];
    const float* ki = (const float*)d_in[3];
    const float* vr = (const float*)d_in[4];
    const float* vi = (const float*)d_in[5];
    ushort* ws = (ushort*)d_ws;   // needs 24 MB: 6 f16 arrays of 2M elems

    hipLaunchKernelGGL(cvt_qk, dim3(8192), dim3(256), 0, stream, qr, qi, kr, ki, ws);
    hipLaunchKernelGGL(cvt_v, dim3(1024), dim3(256), 0, stream, vr, vi, ws + (4l << 21));
    hipLaunchKernelGGL(attn, dim3(256), dim3(1024), 65536, stream, ws, (float*)d_out);
}

// Round 3
// 215.141 us; speedup vs baseline: 1.1714x; 1.1714x over previous
//
#include <hip/hip_runtime.h>

#define N_ 4
#define L_ 1024
#define H_ 8
#define D_ 64

typedef _Float16 f16x8 __attribute__((ext_vector_type(8)));
typedef float f32x4 __attribute__((ext_vector_type(4)));

#define MFMA(A, B, C) __builtin_amdgcn_mfma_f32_16x16x32_f16(A, B, C, 0, 0, 0)

__device__ __forceinline__ ushort f2h(float x) {
    union { _Float16 h; ushort u; } c;
    c.h = (_Float16)x;
    return c.u;
}
__device__ __forceinline__ float h2f(ushort u) {
    union { ushort u; _Float16 h; } c;
    c.u = u;
    return (float)c.h;
}
__device__ __forceinline__ f16x8 ld8(const ushort* p) {
    return *(const f16x8*)p;
}
__device__ __forceinline__ f16x8 negf(f16x8 a) {
    uint4 u = __builtin_bit_cast(uint4, a);
    u.x ^= 0x80008000u; u.y ^= 0x80008000u; u.z ^= 0x80008000u; u.w ^= 0x80008000u;
    return __builtin_bit_cast(f16x8, u);
}

// ---- convert Q,K: fp32 [n][l][h][d] -> f16 [aid][n][h][l][d]
// Q (aid 0,1) is pre-scaled by scale*log2(e) so scores come out as exp2 args.
__global__ void cvt_qk(const float* __restrict__ q_r, const float* __restrict__ q_i,
                       const float* __restrict__ k_r, const float* __restrict__ k_i,
                       ushort* __restrict__ dst) {
    int gid = blockIdx.x * 256 + threadIdx.x;   // 0..2097151 (x4 elems each)
    int aid = gid >> 19;
    int idx = (gid & 0x7FFFF) << 2;             // flat [n][h][l][d]
    int d  = idx & 63;
    int l  = (idx >> 6) & 1023;
    int hh = (idx >> 16) & 7;
    int n  = idx >> 19;
    const float* src = aid == 0 ? q_r : aid == 1 ? q_i : aid == 2 ? k_r : k_i;
    const float sc = (aid < 2) ? 0.18033688011112f : 1.0f;  // (1/8)*log2(e)
    const float4 v = *(const float4*)(src + (((long)n * 1024 + l) * 8 + hh) * 64 + d);
    ushort4 o = make_ushort4(f2h(v.x * sc), f2h(v.y * sc), f2h(v.z * sc), f2h(v.w * sc));
    *(ushort4*)(dst + ((long)aid << 21) + idx) = o;
}

// ---- convert V: fp32 [n][s][h][d] -> f16 transposed [aid][n][h][d][s]
__global__ void cvt_v(const float* __restrict__ vr, const float* __restrict__ vi,
                      ushort* __restrict__ dst) {
    __shared__ ushort t[64][72];
    int bid = blockIdx.x;
    int aid = bid >> 9;
    int b   = bid & 511;
    int s0  = (b & 15) << 6;
    int hh  = (b >> 4) & 7;
    int n   = b >> 7;
    const float* src = aid ? vi : vr;
    int tid = threadIdx.x;            // 256
    int r  = tid >> 4;                // 0..15
    int cq = (tid & 15) << 2;         // 0,4,..,60
#pragma unroll
    for (int it = 0; it < 4; ++it) {
        int s = s0 + it * 16 + r;
        const float4 v = *(const float4*)(src + (((long)n * 1024 + s) * 8 + hh) * 64 + cq);
        t[it * 16 + r][cq + 0] = f2h(v.x);
        t[it * 16 + r][cq + 1] = f2h(v.y);
        t[it * 16 + r][cq + 2] = f2h(v.z);
        t[it * 16 + r][cq + 3] = f2h(v.w);
    }
    __syncthreads();
#pragma unroll
    for (int it = 0; it < 4; ++it) {
        int dd = it * 16 + r;
        ushort4 o;
        o.x = t[cq + 0][dd]; o.y = t[cq + 1][dd]; o.z = t[cq + 2][dd]; o.w = t[cq + 3][dd];
        *(ushort4*)(dst + ((long)aid << 21) + (((long)n * 8 + hh) * 64 + dd) * 1024 + s0 + cq) = o;
    }
}

// scores for sub-block sb of chunk c -> a0 (real exp2-arg), a1 (imag exp2-arg)
// Q pre-scaled, so a0/a1 are directly exp2 arguments.
#define SCORES(c, sbi, a0, a1)                                              \
    do {                                                                    \
        const long soff = (long)((c) * 64 + (sbi) * 16 + col) * 64 + g * 8; \
        f16x8 kr0v = ld8(Kr + soff), kr1v = ld8(Kr + soff + 32);            \
        f16x8 ki0v = ld8(Ki + soff), ki1v = ld8(Ki + soff + 32);            \
        a0 = (f32x4){0.f, 0.f, 0.f, 0.f};                                   \
        a0 = MFMA(qr0, kr0v, a0); a0 = MFMA(qr1, kr1v, a0);                 \
        a0 = MFMA(qi0, negf(ki0v), a0); a0 = MFMA(qi1, negf(ki1v), a0);     \
        a1 = (f32x4){0.f, 0.f, 0.f, 0.f};                                   \
        a1 = MFMA(qr0, ki0v, a1); a1 = MFMA(qr1, ki1v, a1);                 \
        a1 = MFMA(qi0, kr0v, a1); a1 = MFMA(qi1, kr1v, a1);                 \
    } while (0)

#define BFLY(x)                                                             \
    x += __shfl_xor(x, 1); x += __shfl_xor(x, 2);                           \
    x += __shfl_xor(x, 4); x += __shfl_xor(x, 8);

// ---- fused complex attention ----
// grid 256 (XCD-swizzled -> (n, l-tile)), block 1024 = 16 waves.
// wave = (h, sh). No-max softmax: pass1 accumulates exp2 sums per lane,
// deferred butterfly, denominators folded into per-row constants.
__launch_bounds__(1024, 4)
__global__ void attn(const ushort* __restrict__ ws, float* __restrict__ out) {
    extern __shared__ ushort dynlds[];       // 64KB: [sh][h][part][16][64] swizzled
    __shared__ float sst[2][8][2][16];       // [sh][h][part][row] denom partials

    const int tid  = threadIdx.x;
    const int lane = tid & 63;
    const int wv   = tid >> 6;
    const int h    = wv & 7;
    const int sh   = wv >> 3;
    const int col  = lane & 15;
    const int g    = lane >> 4;

    const int bid = blockIdx.x;
    const int nid = (bid & 7) * 32 + (bid >> 3);
    const int n   = nid >> 6;
    const int l0  = (nid & 63) << 4;

    const ushort* wsQr = ws;
    const ushort* wsQi = ws + (1l << 21);
    const ushort* wsKr = ws + (2l << 21);
    const ushort* wsKi = ws + (3l << 21);
    const ushort* wsVr = ws + (4l << 21);   // [n][h][d][s]
    const ushort* wsVi = ws + (5l << 21);

    const int nh = n * H_ + h;
    const ushort* Kr = wsKr + ((long)nh << 16);   // [1024][64]
    const ushort* Ki = wsKi + ((long)nh << 16);
    const ushort* Vr = wsVr + ((long)nh << 16);   // [64][1024]
    const ushort* Vi = wsVi + ((long)nh << 16);

    const long qoff = ((long)nh * 1024 + l0 + col) * 64 + g * 8;
    const f16x8 qr0 = ld8(wsQr + qoff), qr1 = ld8(wsQr + qoff + 32);
    const f16x8 qi0 = ld8(wsQi + qoff), qi1 = ld8(wsQi + qoff + 32);

    // ---------------- pass 1: exp-sum denominators (no max needed) ----------
    float dR0 = 0.f, dR1 = 0.f, dR2 = 0.f, dR3 = 0.f;
    float dI0 = 0.f, dI1 = 0.f, dI2 = 0.f, dI3 = 0.f;
    for (int cc = 0; cc < 8; ++cc) {
        const int c = sh * 8 + cc;
#pragma unroll
        for (int sb = 0; sb < 4; ++sb) {
            f32x4 a0, a1;
            SCORES(c, sb, a0, a1);
            dR0 += exp2f(a0[0]); dR1 += exp2f(a0[1]);
            dR2 += exp2f(a0[2]); dR3 += exp2f(a0[3]);
            dI0 += exp2f(a1[0]); dI1 += exp2f(a1[1]);
            dI2 += exp2f(a1[2]); dI3 += exp2f(a1[3]);
        }
    }
    BFLY(dR0) BFLY(dR1) BFLY(dR2) BFLY(dR3)
    BFLY(dI0) BFLY(dI1) BFLY(dI2) BFLY(dI3)

    if (col == 0) {
        sst[sh][h][0][4 * g + 0] = dR0; sst[sh][h][0][4 * g + 1] = dR1;
        sst[sh][h][0][4 * g + 2] = dR2; sst[sh][h][0][4 * g + 3] = dR3;
        sst[sh][h][1][4 * g + 0] = dI0; sst[sh][h][1][4 * g + 1] = dI1;
        sst[sh][h][1][4 * g + 2] = dI2; sst[sh][h][1][4 * g + 3] = dI3;
    }
    __syncthreads();

    // per-row fused normalizer: w = exp2(arg - log2(denom))
    const float cR0 = log2f(sst[0][h][0][4 * g + 0] + sst[1][h][0][4 * g + 0]);
    const float cR1 = log2f(sst[0][h][0][4 * g + 1] + sst[1][h][0][4 * g + 1]);
    const float cR2 = log2f(sst[0][h][0][4 * g + 2] + sst[1][h][0][4 * g + 2]);
    const float cR3 = log2f(sst[0][h][0][4 * g + 3] + sst[1][h][0][4 * g + 3]);
    const float cI0 = log2f(sst[0][h][1][4 * g + 0] + sst[1][h][1][4 * g + 0]);
    const float cI1 = log2f(sst[0][h][1][4 * g + 1] + sst[1][h][1][4 * g + 1]);
    const float cI2 = log2f(sst[0][h][1][4 * g + 2] + sst[1][h][1][4 * g + 2]);
    const float cI3 = log2f(sst[0][h][1][4 * g + 3] + sst[1][h][1][4 * g + 3]);

    // ---------------- pass 2: apply ----------------
    f32x4 uRe[4], uIm[4];
#pragma unroll
    for (int db = 0; db < 4; ++db) {
        uRe[db] = (f32x4){0.f, 0.f, 0.f, 0.f};
        uIm[db] = (f32x4){0.f, 0.f, 0.f, 0.f};
    }

    const long OFF_UI = 2097152;
    const long OFF_AR = 4194304;
    const long OFF_AI = 8388608;

    ushort* wbr = dynlds + (((sh * 8 + h) * 2 + 0) << 10);
    ushort* wbi = dynlds + (((sh * 8 + h) * 2 + 1) << 10);

    for (int cc = 0; cc < 8; ++cc) {
        const int c = sh * 8 + cc;
#pragma unroll
        for (int sb = 0; sb < 4; ++sb) {
            f32x4 a0, a1;
            SCORES(c, sb, a0, a1);
            const int u0 = sb * 16 + col;
            {
                const int row = 4 * g + 0, us = u0 ^ ((row & 7) << 3);
                wbr[row * 64 + us] = f2h(exp2f(a0[0] - cR0));
                wbi[row * 64 + us] = f2h(exp2f(a1[0] - cI0));
            }
            {
                const int row = 4 * g + 1, us = u0 ^ ((row & 7) << 3);
                wbr[row * 64 + us] = f2h(exp2f(a0[1] - cR1));
                wbi[row * 64 + us] = f2h(exp2f(a1[1] - cI1));
            }
            {
                const int row = 4 * g + 2, us = u0 ^ ((row & 7) << 3);
                wbr[row * 64 + us] = f2h(exp2f(a0[2] - cR2));
                wbi[row * 64 + us] = f2h(exp2f(a1[2] - cI2));
            }
            {
                const int row = 4 * g + 3, us = u0 ^ ((row & 7) << 3);
                wbr[row * 64 + us] = f2h(exp2f(a0[3] - cR3));
                wbi[row * 64 + us] = f2h(exp2f(a1[3] - cI3));
            }
        }
        __syncthreads();
        // u MFMA: A = w (own head/half), B = V^T slices. swizzled b128 reads.
        {
            const int xr  = ((g ^ (col & 7)) << 3);
            const int xr2 = (((g + 4) ^ (col & 7)) << 3);
            f16x8 wr0 = ld8(&wbr[col * 64 + xr]);
            f16x8 wr1 = ld8(&wbr[col * 64 + xr2]);
            f16x8 wi0 = ld8(&wbi[col * 64 + xr]);
            f16x8 wi1 = ld8(&wbi[col * 64 + xr2]);
            f16x8 wn0 = negf(wi0), wn1 = negf(wi1);
#pragma unroll
            for (int db = 0; db < 4; ++db) {
                const ushort* vrb = Vr + (long)(db * 16 + col) * 1024 + c * 64 + g * 8;
                f16x8 vr0 = ld8(vrb), vr1 = ld8(vrb + 32);
                const ushort* vib = Vi + (long)(db * 16 + col) * 1024 + c * 64 + g * 8;
                f16x8 vi0 = ld8(vib), vi1 = ld8(vib + 32);
                uRe[db] = MFMA(wr0, vr0, uRe[db]); uRe[db] = MFMA(wr1, vr1, uRe[db]);
                uRe[db] = MFMA(wn0, vi0, uRe[db]); uRe[db] = MFMA(wn1, vi1, uRe[db]);
                uIm[db] = MFMA(wr0, vi0, uIm[db]); uIm[db] = MFMA(wr1, vi1, uIm[db]);
                uIm[db] = MFMA(wi0, vr0, uIm[db]); uIm[db] = MFMA(wi1, vr1, uIm[db]);
            }
        }
        // a slice: rows 2h, 2h+1 of own sh's current chunk, summed over heads
#pragma unroll
        for (int rr = 0; rr < 2; ++rr) {
            const int l = 2 * h + rr;
            const int us = lane ^ ((l & 7) << 3);
            float s_r = 0.f, s_i = 0.f;
#pragma unroll
            for (int hh = 0; hh < 8; ++hh) {
                s_r += h2f(dynlds[(((sh * 8 + hh) * 2 + 0) << 10) + l * 64 + us]);
                s_i += h2f(dynlds[(((sh * 8 + hh) * 2 + 1) << 10) + l * 64 + us]);
            }
            const long ai = ((long)n * L_ + l0 + l) * 1024 + c * 64 + lane;
            out[OFF_AR + ai] = s_r * 0.125f;
            out[OFF_AI + ai] = s_i * 0.125f;
        }
        __syncthreads();
    }

    // ---------------- combine u across s-halves, write ----------------
    float* uc = (float*)dynlds;   // 64KB alias, safe after trailing barrier
    if (sh == 1) {
#pragma unroll
        for (int db = 0; db < 4; ++db) {
            *(f32x4*)&uc[(((h * 2 + 0) * 4 + db) * 64 + lane) * 4] = uRe[db];
            *(f32x4*)&uc[(((h * 2 + 1) * 4 + db) * 64 + lane) * 4] = uIm[db];
        }
    }
    __syncthreads();
    if (sh == 0) {
#pragma unroll
        for (int db = 0; db < 4; ++db) {
            f32x4 o0 = *(f32x4*)&uc[(((h * 2 + 0) * 4 + db) * 64 + lane) * 4];
            f32x4 o1 = *(f32x4*)&uc[(((h * 2 + 1) * 4 + db) * 64 + lane) * 4];
            uRe[db] += o0;
            uIm[db] += o1;
#pragma unroll
            for (int r = 0; r < 4; ++r) {
                const int l = l0 + 4 * g + r;
                const int d = db * 16 + col;
                const long base = (((long)n * L_ + l) * H_ + h) * D_ + d;
                out[base] = uRe[db][r];
                out[OFF_UI + base] = uIm[db][r];
            }
        }
    }
}

extern "C" void kernel_launch(void* const* d_in, const int* in_sizes, int n_in,
                              void* d_out, int out_size, void* d_ws, size_t ws_size,
                              hipStream_t stream) {
    const float* qr = (const float*)d_in[0];
    const float* qi = (const float*)d_in[1];
    const float* kr = (const float*)d_in[2];
    const float* ki = (const float*)d_in[3];
    const float* vr = (const float*)d_in[4];
    const float* vi = (const float*)d_in[5];
    ushort* ws = (ushort*)d_ws;   // needs 24 MB: 6 f16 arrays of 2M elems

    hipLaunchKernelGGL(cvt_qk, dim3(8192), dim3(256), 0, stream, qr, qi, kr, ki, ws);
    hipLaunchKernelGGL(cvt_v, dim3(1024), dim3(256), 0, stream, vr, vi, ws + (4l << 21));
    hipLaunchKernelGGL(attn, dim3(256), dim3(1024), 65536, stream, ws, (float*)d_out);
}